// Round 3
// baseline (76.530 us; speedup 1.0000x reference)
//
#include <hip/hip_runtime.h>
#include <hip/hip_bf16.h>

#define NB 16
#define N_IN 512
#define N_OUT 4096
#define OUT_CH 64
#define M_TILE 128               // 2 m per thread
#define NCHUNK 4                 // 4 waves split the n loop
#define NPER (N_IN / NCHUNK)     // 128 n per thread

__global__ __launch_bounds__(256) void convdeepset_kernel(
    const float* __restrict__ x,
    const float* __restrict__ y,
    const float* __restrict__ t,
    const float* __restrict__ sigma,
    const float* __restrict__ W,
    const float* __restrict__ bias,
    float* __restrict__ out)
{
    __shared__ float4 pqyx[N_IN];        // (p = k*x^2, q = -2k*x, y, x)
    __shared__ float red0[2][256];
    __shared__ float red1[2][256];
    __shared__ float f0[M_TILE];
    __shared__ float f1[M_TILE];
    __shared__ float wf[OUT_CH * 2];
    __shared__ float bf[OUT_CH];

    const int tid = threadIdx.x;
    const int blk = blockIdx.x;          // b * (N_OUT/M_TILE) + mtile
    const int b   = blk >> 5;            // N_OUT/M_TILE == 32
    const int mt  = blk & 31;
    const int m0  = mt * M_TILE;

    // k_c = -0.5/exp(sigma_c)^2 * log2(e)  (exp2-ready)
    const float LOG2E = 1.4426950408889634f;
    const float s0 = sigma[0];
    const float s1 = sigma[1];
    const float k0 = -0.5f * __builtin_amdgcn_exp2f(-2.0f * s0 * LOG2E) * LOG2E;
    const float k1 = -0.5f * __builtin_amdgcn_exp2f(-2.0f * s1 * LOG2E) * LOG2E;
    const bool fast = (k0 == k1);

    // stage precomputed per-n terms into LDS
    for (int i = tid; i < N_IN; i += 256) {
        float xv = x[b * N_IN + i];
        float yv = y[b * N_IN + i];
        float4 f;
        f.x = k0 * xv * xv;              // p
        f.y = -2.0f * k0 * xv;           // q
        f.z = yv;
        f.w = xv;
        pqyx[i] = f;
    }
    if (tid < OUT_CH * 2) wf[tid] = W[tid];
    if (tid < OUT_CH)     bf[tid] = bias[tid];
    __syncthreads();

    const int l  = tid & 63;             // lane-in-wave = m offset
    const int nc = tid >> 6;             // wave id = n chunk
    const int nbase = nc * NPER;

    const float t0 = t[b * N_OUT + m0 + l];
    const float t1 = t[b * N_OUT + m0 + 64 + l];

    float a00 = 0.0f, a01 = 0.0f;        // dens/conv for m = m0+l
    float a10 = 0.0f, a11 = 0.0f;        // dens/conv for m = m0+64+l

    if (fast) {
        // exp2(k(x-t)^2) = exp2(fma(q,t,p)) * exp2(k t^2); fold the latter out
        #pragma unroll 4
        for (int i = 0; i < NPER; ++i) {
            float4 f = pqyx[nbase + i];
            float e0 = __builtin_amdgcn_exp2f(fmaf(f.y, t0, f.x));
            float e1 = __builtin_amdgcn_exp2f(fmaf(f.y, t1, f.x));
            a00 += e0;
            a01 = fmaf(f.z, e0, a01);
            a10 += e1;
            a11 = fmaf(f.z, e1, a11);
        }
        const float et0 = __builtin_amdgcn_exp2f(k0 * t0 * t0);
        const float et1 = __builtin_amdgcn_exp2f(k0 * t1 * t1);
        a00 *= et0; a01 *= et0;
        a10 *= et1; a11 *= et1;
    } else {
        #pragma unroll 4
        for (int i = 0; i < NPER; ++i) {
            float4 f = pqyx[nbase + i];
            float dx0 = f.w - t0, dx1 = f.w - t1;
            float d20 = dx0 * dx0, d21 = dx1 * dx1;
            a00 += __builtin_amdgcn_exp2f(k0 * d20);
            a01 = fmaf(f.z, __builtin_amdgcn_exp2f(k1 * d20), a01);
            a10 += __builtin_amdgcn_exp2f(k0 * d21);
            a11 = fmaf(f.z, __builtin_amdgcn_exp2f(k1 * d21), a11);
        }
    }

    red0[0][tid] = a00; red1[0][tid] = a01;
    red0[1][tid] = a10; red1[1][tid] = a11;
    __syncthreads();

    if (tid < M_TILE) {
        const int h = tid >> 6, ll = tid & 63;
        float dens = red0[h][ll] + red0[h][ll + 64] + red0[h][ll + 128] + red0[h][ll + 192];
        float conv = red1[h][ll] + red1[h][ll + 64] + red1[h][ll + 128] + red1[h][ll + 192];
        f0[tid] = dens;
        f1[tid] = conv / (dens + 1e-8f);
    }
    __syncthreads();

    // epilogue: out[b, m, o] = W[o,0]*dens + W[o,1]*normalized + b[o]
    const size_t obase = (size_t)(b * N_OUT + m0) * OUT_CH;
    for (int p = tid; p < M_TILE * OUT_CH / 4; p += 256) {
        int mloc = p >> 4;               // 16 float4s per m
        int o    = (p & 15) * 4;
        float d = f0[mloc], nrm = f1[mloc];
        float4 v;
        v.x = fmaf(wf[2 * (o + 0) + 0], d, fmaf(wf[2 * (o + 0) + 1], nrm, bf[o + 0]));
        v.y = fmaf(wf[2 * (o + 1) + 0], d, fmaf(wf[2 * (o + 1) + 1], nrm, bf[o + 1]));
        v.z = fmaf(wf[2 * (o + 2) + 0], d, fmaf(wf[2 * (o + 2) + 1], nrm, bf[o + 2]));
        v.w = fmaf(wf[2 * (o + 3) + 0], d, fmaf(wf[2 * (o + 3) + 1], nrm, bf[o + 3]));
        *reinterpret_cast<float4*>(out + obase + (size_t)mloc * OUT_CH + o) = v;
    }
}

extern "C" void kernel_launch(void* const* d_in, const int* in_sizes, int n_in,
                              void* d_out, int out_size, void* d_ws, size_t ws_size,
                              hipStream_t stream) {
    const float* x     = (const float*)d_in[0];
    const float* y     = (const float*)d_in[1];
    const float* t     = (const float*)d_in[2];
    const float* sigma = (const float*)d_in[3];
    const float* W     = (const float*)d_in[4];
    const float* bias  = (const float*)d_in[5];
    float* out = (float*)d_out;

    dim3 grid(NB * (N_OUT / M_TILE));    // 16 * 32 = 512 blocks
    convdeepset_kernel<<<grid, 256, 0, stream>>>(x, y, t, sigma, W, bias, out);
}

// Round 4
// 74.553 us; speedup vs baseline: 1.0265x; 1.0265x over previous
//
#include <hip/hip_runtime.h>
#include <hip/hip_bf16.h>

#define NB 16
#define N_IN 512
#define N_OUT 4096
#define OUT_CH 64
#define M_TILE 128               // 2 m per thread
#define NCHUNK 4                 // 4 waves split the n loop
#define NPER (N_IN / NCHUNK)     // 128 n per thread
#define NQUAD (NPER / 4)         // 32 float4 quads per thread

__global__ __launch_bounds__(256) void convdeepset_kernel(
    const float* __restrict__ x,
    const float* __restrict__ y,
    const float* __restrict__ t,
    const float* __restrict__ sigma,
    const float* __restrict__ W,
    const float* __restrict__ bias,
    float* __restrict__ out)
{
    __shared__ float sp[N_IN];           // p = k*x^2   (slow path: x)
    __shared__ float sq[N_IN];           // q = -2k*x   (slow path: unused)
    __shared__ float sy[N_IN];           // y
    __shared__ float red0[2][256];
    __shared__ float red1[2][256];
    __shared__ float f0[M_TILE];
    __shared__ float f1[M_TILE];
    __shared__ float wf[OUT_CH * 2];
    __shared__ float bf[OUT_CH];

    const int tid = threadIdx.x;
    const int blk = blockIdx.x;          // b * (N_OUT/M_TILE) + mtile
    const int b   = blk >> 5;            // N_OUT/M_TILE == 32
    const int mt  = blk & 31;
    const int m0  = mt * M_TILE;

    // k_c = -0.5/exp(sigma_c)^2 * log2(e)  (exp2-ready)
    const float LOG2E = 1.4426950408889634f;
    const float s0 = sigma[0];
    const float s1 = sigma[1];
    const float k0 = -0.5f * __builtin_amdgcn_exp2f(-2.0f * s0 * LOG2E) * LOG2E;
    const float k1 = -0.5f * __builtin_amdgcn_exp2f(-2.0f * s1 * LOG2E) * LOG2E;
    const bool fast = (k0 == k1);

    // stage per-n terms into LDS (SoA so the hot loop reads 3 b128 per 4 n)
    for (int i = tid; i < N_IN; i += 256) {
        float xv = x[b * N_IN + i];
        float yv = y[b * N_IN + i];
        if (fast) {
            sp[i] = k0 * xv * xv;        // p
            sq[i] = -2.0f * k0 * xv;     // q
        } else {
            sp[i] = xv;                  // raw x for slow path
            sq[i] = 0.0f;
        }
        sy[i] = yv;
    }
    if (tid < OUT_CH * 2) wf[tid] = W[tid];
    if (tid < OUT_CH)     bf[tid] = bias[tid];
    __syncthreads();

    const int l  = tid & 63;             // lane-in-wave = m offset
    const int nc = tid >> 6;             // wave id = n chunk
    const int qbase = nc * NQUAD;        // float4-quad base

    const float t0 = t[b * N_OUT + m0 + l];
    const float t1 = t[b * N_OUT + m0 + 64 + l];

    float a00 = 0.0f, a01 = 0.0f;        // dens/conv for m = m0+l
    float a10 = 0.0f, a11 = 0.0f;        // dens/conv for m = m0+64+l

    const float4* sp4 = reinterpret_cast<const float4*>(sp);
    const float4* sq4 = reinterpret_cast<const float4*>(sq);
    const float4* sy4 = reinterpret_cast<const float4*>(sy);

    if (fast) {
        // exp2(k(x-t)^2) = exp2(fma(q,t,p)) * exp2(k t^2); fold the latter out.
        // max exponent of fma(q,t,p) is 72 for x,t in [0,1], k=-72 -> no overflow.
        #pragma unroll 4
        for (int qi = 0; qi < NQUAD; ++qi) {
            float4 p4 = sp4[qbase + qi];
            float4 q4 = sq4[qbase + qi];
            float4 y4 = sy4[qbase + qi];
            {
                float e0 = __builtin_amdgcn_exp2f(fmaf(q4.x, t0, p4.x));
                float e1 = __builtin_amdgcn_exp2f(fmaf(q4.x, t1, p4.x));
                a00 += e0; a01 = fmaf(y4.x, e0, a01);
                a10 += e1; a11 = fmaf(y4.x, e1, a11);
            }
            {
                float e0 = __builtin_amdgcn_exp2f(fmaf(q4.y, t0, p4.y));
                float e1 = __builtin_amdgcn_exp2f(fmaf(q4.y, t1, p4.y));
                a00 += e0; a01 = fmaf(y4.y, e0, a01);
                a10 += e1; a11 = fmaf(y4.y, e1, a11);
            }
            {
                float e0 = __builtin_amdgcn_exp2f(fmaf(q4.z, t0, p4.z));
                float e1 = __builtin_amdgcn_exp2f(fmaf(q4.z, t1, p4.z));
                a00 += e0; a01 = fmaf(y4.z, e0, a01);
                a10 += e1; a11 = fmaf(y4.z, e1, a11);
            }
            {
                float e0 = __builtin_amdgcn_exp2f(fmaf(q4.w, t0, p4.w));
                float e1 = __builtin_amdgcn_exp2f(fmaf(q4.w, t1, p4.w));
                a00 += e0; a01 = fmaf(y4.w, e0, a01);
                a10 += e1; a11 = fmaf(y4.w, e1, a11);
            }
        }
        const float et0 = __builtin_amdgcn_exp2f(k0 * t0 * t0);
        const float et1 = __builtin_amdgcn_exp2f(k0 * t1 * t1);
        a00 *= et0; a01 *= et0;
        a10 *= et1; a11 *= et1;
    } else {
        #pragma unroll 4
        for (int qi = 0; qi < NQUAD; ++qi) {
            float4 x4 = sp4[qbase + qi];
            float4 y4 = sy4[qbase + qi];
            float xv[4] = {x4.x, x4.y, x4.z, x4.w};
            float yv[4] = {y4.x, y4.y, y4.z, y4.w};
            #pragma unroll
            for (int j = 0; j < 4; ++j) {
                float dx0 = xv[j] - t0, dx1 = xv[j] - t1;
                float d20 = dx0 * dx0, d21 = dx1 * dx1;
                a00 += __builtin_amdgcn_exp2f(k0 * d20);
                a01 = fmaf(yv[j], __builtin_amdgcn_exp2f(k1 * d20), a01);
                a10 += __builtin_amdgcn_exp2f(k0 * d21);
                a11 = fmaf(yv[j], __builtin_amdgcn_exp2f(k1 * d21), a11);
            }
        }
    }

    red0[0][tid] = a00; red1[0][tid] = a01;
    red0[1][tid] = a10; red1[1][tid] = a11;
    __syncthreads();

    if (tid < M_TILE) {
        const int h = tid >> 6, ll = tid & 63;
        float dens = red0[h][ll] + red0[h][ll + 64] + red0[h][ll + 128] + red0[h][ll + 192];
        float conv = red1[h][ll] + red1[h][ll + 64] + red1[h][ll + 128] + red1[h][ll + 192];
        f0[tid] = dens;
        f1[tid] = conv / (dens + 1e-8f);
    }
    __syncthreads();

    // epilogue: out[b, m, o] = W[o,0]*dens + W[o,1]*normalized + b[o]
    const size_t obase = (size_t)(b * N_OUT + m0) * OUT_CH;
    for (int p = tid; p < M_TILE * OUT_CH / 4; p += 256) {
        int mloc = p >> 4;               // 16 float4s per m
        int o    = (p & 15) * 4;
        float d = f0[mloc], nrm = f1[mloc];
        float4 v;
        v.x = fmaf(wf[2 * (o + 0) + 0], d, fmaf(wf[2 * (o + 0) + 1], nrm, bf[o + 0]));
        v.y = fmaf(wf[2 * (o + 1) + 0], d, fmaf(wf[2 * (o + 1) + 1], nrm, bf[o + 1]));
        v.z = fmaf(wf[2 * (o + 2) + 0], d, fmaf(wf[2 * (o + 2) + 1], nrm, bf[o + 2]));
        v.w = fmaf(wf[2 * (o + 3) + 0], d, fmaf(wf[2 * (o + 3) + 1], nrm, bf[o + 3]));
        *reinterpret_cast<float4*>(out + obase + (size_t)mloc * OUT_CH + o) = v;
    }
}

extern "C" void kernel_launch(void* const* d_in, const int* in_sizes, int n_in,
                              void* d_out, int out_size, void* d_ws, size_t ws_size,
                              hipStream_t stream) {
    const float* x     = (const float*)d_in[0];
    const float* y     = (const float*)d_in[1];
    const float* t     = (const float*)d_in[2];
    const float* sigma = (const float*)d_in[3];
    const float* W     = (const float*)d_in[4];
    const float* bias  = (const float*)d_in[5];
    float* out = (float*)d_out;

    dim3 grid(NB * (N_OUT / M_TILE));    // 16 * 32 = 512 blocks
    convdeepset_kernel<<<grid, 256, 0, stream>>>(x, y, t, sigma, W, bias, out);
}